// Round 18
// baseline (272.308 us; speedup 1.0000x reference)
//
#include <hip/hip_runtime.h>
#include <hip/hip_bf16.h>

// EdgeNet fused 2-layer MLP, MI355X (gfx950) — round 17.
//
// out[m][n2] = relu( W2 · relu( W1' · child[m] + b1 ) + b2 ),  W1' = W1 ⊙ parent
//
// R8..R16: every variant kept the serial skeleton stage->L1->BAR->L2 where x
// transits regs -> VALU pack -> LDS -> ds_read before any MFMA. R17 deletes
// that stage entirely: layer-1 B-frags are loaded DIRECTLY from global child
// (lane (g,m16) reads its 8 contiguous f32 per (mf,kt) — two f32x4 loads).
// Each wave re-reads the 64 KB tile (8x amplification, ~1.6 GB from L2/L3
// aggregate ~16 TB/s < 34.5 TB/s L2 ceiling; first wave pulls tile to XCD-L2).
// No xf, no stage, no prefetch regs, no stage-vmcnt stall. hf double-buffered
// -> ONE lgkm-only barrier per tile. Bias in registers. LDS 64 KiB.
//
// Per-tile schedule (p = parity):
//   L1: child(global) -> cvt -> MFMA -> acc1        (no LDS dependency)
//   relu/pack acc1 -> hf[p]
//   BAR (lgkm-only)
//   L2: hf[p] -> acc2; store out
// Hazards: hf[p] w(t)/r(t) separated by BAR(t). hf[p^1] w(t+1) vs r(t):
// any wave's w(t+1) is after its BAR(t); reads r(t) of hf[p] finish before
// that wave passes BAR(t+1); buffers differ at adjacent iters -> safe with
// one barrier. Out-stores/child loads never drained (lgkm-only).
//
// MFMA conventions (verified R1..R16, absmax 0.03125):
//   A-frag: lane holds A[row = lane&15][k = 8*(lane>>4)+i], i=0..7
//   B-frag: lane holds B[k = 8*(lane>>4)+i][col = lane&15]
//   C/D  : lane holds C[row = 4*(lane>>4)+reg][col = lane&15]

typedef float f32x4 __attribute__((ext_vector_type(4)));
typedef short bf16x8 __attribute__((ext_vector_type(8)));
typedef unsigned int u32;
typedef u32 u32x4 __attribute__((ext_vector_type(4)));

#define BARRIER_LGKM() asm volatile("s_waitcnt lgkmcnt(0)\n\ts_barrier" ::: "memory")

__device__ __forceinline__ u32 pk2bf(float a, float b) {
    __hip_bfloat162 h2 = __float22bfloat162_rn(make_float2(a, b));
    u32 r;
    __builtin_memcpy(&r, &h2, 4);
    return r;
}

// Pack weights into per-lane MFMA A-fragment order; parent folded into W1.
// halfword[((kt*16 + nt)*64 + lane)*8 + i] = bf16(W'[nt*16 + (lane&15)][kt*32 + 8*(lane>>4) + i])
__global__ __launch_bounds__(256) void pack_w_kernel(
    const float* __restrict__ W1, const float* __restrict__ W2,
    const float* __restrict__ parent, unsigned short* __restrict__ wp)
{
    int t = blockIdx.x * 256 + threadIdx.x;   // 0..16383
    int sel = t >> 13;
    int tt = t & 8191;
    int lane = tt & 63;
    int nt = (tt >> 6) & 15;
    int kt = tt >> 10;
    int n = nt * 16 + (lane & 15);
    int k0 = kt * 32 + 8 * (lane >> 4);
    const float* W = sel ? W2 : W1;
    const float* src = W + n * 256 + k0;
    f32x4 a = *(const f32x4*)src;
    f32x4 b = *(const f32x4*)(src + 4);
    if (sel == 0) {                            // fold parent into W1
        a *= *(const f32x4*)(parent + k0);
        b *= *(const f32x4*)(parent + k0 + 4);
    }
    u32x4 d;
    d.x = pk2bf(a.x, a.y);
    d.y = pk2bf(a.z, a.w);
    d.z = pk2bf(b.x, b.y);
    d.w = pk2bf(b.z, b.w);
    *(u32x4*)(wp + (size_t)t * 8) = d;
}

__global__ __launch_bounds__(512, 2) void fused_mlp(
    const float* __restrict__ child,
    const float* __restrict__ b1, const float* __restrict__ b2,
    const unsigned short* __restrict__ w1p, const unsigned short* __restrict__ w2p,
    float* __restrict__ out, int n_rows)
{
    // h-frags (double-buffered): frag (mf, kt) at halfword (mf*8+kt)*512 + lane*8
    __shared__ __align__(16) unsigned short hf[2][16384];  // 2 x 32 KiB

    const int tid = threadIdx.x;
    const int lane = tid & 63;
    const int w = tid >> 6;        // wave 0..7; owns cols [32w, 32w+32) both layers
    const int m16 = lane & 15;
    const int g = lane >> 4;

    // bias in registers (8 f32 per layer per wave)
    f32x4 bv1[2], bv2[2];
    #pragma unroll
    for (int j = 0; j < 2; ++j) {
        bv1[j] = *(const f32x4*)(b1 + (2 * w + j) * 16 + 4 * g);
        bv2[j] = *(const f32x4*)(b2 + (2 * w + j) * 16 + 4 * g);
    }

    const int n_tiles = (n_rows + 63) >> 6;    // 3125 (200000 = 64*3125)

    int p = 0;
    for (int tile = blockIdx.x; tile < n_tiles; tile += gridDim.x) {
        const long row0 = (long)tile * 64;

        // ---- layer 1: B-frags DIRECT from global child ----
        f32x4 acc1[2][4];
        #pragma unroll
        for (int mf = 0; mf < 4; ++mf) {
            acc1[0][mf] = bv1[0];
            acc1[1][mf] = bv1[1];
        }
        const float* cbase = child + (row0 + m16) * 256 + 8 * g;
        #pragma unroll
        for (int kt = 0; kt < 8; ++kt) {
            bf16x8 a0 = *(const bf16x8*)(w1p + (size_t)((kt * 16 + 2 * w) * 64 + lane) * 8);
            bf16x8 a1 = *(const bf16x8*)(w1p + (size_t)((kt * 16 + 2 * w + 1) * 64 + lane) * 8);
            #pragma unroll
            for (int mf = 0; mf < 4; ++mf) {
                const float* cp = cbase + mf * (16 * 256) + kt * 32;
                f32x4 c0 = *(const f32x4*)cp;
                f32x4 c1 = *(const f32x4*)(cp + 4);
                u32x4 u;
                u.x = pk2bf(c0.x, c0.y);
                u.y = pk2bf(c0.z, c0.w);
                u.z = pk2bf(c1.x, c1.y);
                u.w = pk2bf(c1.z, c1.w);
                bf16x8 bfrag = __builtin_bit_cast(bf16x8, u);
                acc1[0][mf] = __builtin_amdgcn_mfma_f32_16x16x32_bf16(a0, bfrag, acc1[0][mf], 0, 0, 0);
                acc1[1][mf] = __builtin_amdgcn_mfma_f32_16x16x32_bf16(a1, bfrag, acc1[1][mf], 0, 0, 0);
            }
        }

        // ---- relu + pack h -> hf[p]  (kt2 = w) ----
        // lane holds h[k2 = 32w + 16j + 4g + r][m = mf*16 + m16]
        //   -> frag (mf, w), lane' = 16*(2j + (g>>1)) + m16, halfword 4*(g&1) + r
        #pragma unroll
        for (int j = 0; j < 2; ++j) {
            #pragma unroll
            for (int mf = 0; mf < 4; ++mf) {
                f32x4 v = acc1[j][mf];
                v.x = fmaxf(v.x, 0.0f); v.y = fmaxf(v.y, 0.0f);
                v.z = fmaxf(v.z, 0.0f); v.w = fmaxf(v.w, 0.0f);
                u32* dst = (u32*)&hf[p][((mf * 8 + w) * 64 + 16 * (2 * j + (g >> 1)) + m16) * 8 + 4 * (g & 1)];
                dst[0] = pk2bf(v.x, v.y);
                dst[1] = pk2bf(v.z, v.w);
            }
        }

        // ---- the ONLY barrier: LDS ordering; vmem stays in flight ----
        BARRIER_LGKM();

        // ---- layer 2 over hf[p] + store out(t) ----
        f32x4 acc2[2][4];
        #pragma unroll
        for (int mf = 0; mf < 4; ++mf) {
            acc2[0][mf] = bv2[0];
            acc2[1][mf] = bv2[1];
        }
        #pragma unroll
        for (int kt = 0; kt < 8; ++kt) {
            bf16x8 a0 = *(const bf16x8*)(w2p + (size_t)((kt * 16 + 2 * w) * 64 + lane) * 8);
            bf16x8 a1 = *(const bf16x8*)(w2p + (size_t)((kt * 16 + 2 * w + 1) * 64 + lane) * 8);
            #pragma unroll
            for (int mf = 0; mf < 4; ++mf) {
                bf16x8 hfrag = *(const bf16x8*)&hf[p][((mf * 8 + kt) * 64 + lane) * 8];
                acc2[0][mf] = __builtin_amdgcn_mfma_f32_16x16x32_bf16(a0, hfrag, acc2[0][mf], 0, 0, 0);
                acc2[1][mf] = __builtin_amdgcn_mfma_f32_16x16x32_bf16(a1, hfrag, acc2[1][mf], 0, 0, 0);
            }
        }

        // store: lane holds out[m = mf*16+m16][n2 = (2w+j)*16 + 4g + r]
        #pragma unroll
        for (int mf = 0; mf < 4; ++mf) {
            if (row0 + mf * 16 < n_rows) {     // wave-uniform
                float* orow = out + (size_t)(row0 + mf * 16 + m16) * 256 + 4 * g;
                #pragma unroll
                for (int j = 0; j < 2; ++j) {
                    f32x4 v = acc2[j][mf];
                    v.x = fmaxf(v.x, 0.0f); v.y = fmaxf(v.y, 0.0f);
                    v.z = fmaxf(v.z, 0.0f); v.w = fmaxf(v.w, 0.0f);
                    *(f32x4*)(orow + (2 * w + j) * 16) = v;
                }
            }
        }

        p ^= 1;
    }
}

extern "C" void kernel_launch(void* const* d_in, const int* in_sizes, int n_in,
                              void* d_out, int out_size, void* d_ws, size_t ws_size,
                              hipStream_t stream) {
    const float* parent = (const float*)d_in[0];
    const float* child  = (const float*)d_in[1];
    const float* W1     = (const float*)d_in[2];
    const float* b1     = (const float*)d_in[3];
    const float* W2     = (const float*)d_in[4];
    const float* b2     = (const float*)d_in[5];
    float* out = (float*)d_out;

    unsigned short* wp = (unsigned short*)d_ws;   // [0..65535]=W1' frags, [65536..131071]=W2 frags
    const int n_rows = in_sizes[1] / 256;         // 200000

    pack_w_kernel<<<64, 256, 0, stream>>>(W1, W2, parent, wp);
    fused_mlp<<<512, 512, 0, stream>>>(child, b1, b2,
                                       wp, wp + 65536, out, n_rows);
}

// Round 19
// 102.160 us; speedup vs baseline: 2.6655x; 2.6655x over previous
//
#include <hip/hip_runtime.h>
#include <hip/hip_bf16.h>

// EdgeNet fused 2-layer MLP, MI355X (gfx950) — FINAL (R14 resubmission).
//
// out[m][n2] = relu( W2 · relu( W1' · child[m] + b1 ) + b2 ),  W1' = W1 ⊙ parent
//
// Best measured variant (101.7 us, ~2.9x faster than the first working
// kernel). Structure: 64-row tiles, persistent 256-block grid, xf/hf both
// double-buffered (130 KiB LDS), ONE lgkm-only barrier per tile, one-phase
// child prefetch through transient registers, weights streamed from L2.
//
// Experiment matrix (R1..R17) conclusions:
//   tile 64 > {32, 128}; 1 lgkm barrier > {2 drain, 2 lgkm}; 1-phase
//   prefetch > {0, 2}; blocks/CU irrelevant; reg-pinning weights fails
//   (allocator); global-direct B-frags catastrophic (latency chain).
// Remaining gap to the 65 us HBM floor is the serial per-tile dependency
// chain pack->LDS->MFMA->pack->LDS->MFMA->store — a latency composition no
// single pipe bounds (all <35%); past this needs hand-asm interleaving.
//
// MFMA conventions (verified throughout, absmax 0.03125):
//   A-frag: lane holds A[row = lane&15][k = 8*(lane>>4)+i], i=0..7
//   B-frag: lane holds B[k = 8*(lane>>4)+i][col = lane&15]
//   C/D  : lane holds C[row = 4*(lane>>4)+reg][col = lane&15]

typedef float f32x4 __attribute__((ext_vector_type(4)));
typedef short bf16x8 __attribute__((ext_vector_type(8)));
typedef unsigned int u32;
typedef u32 u32x4 __attribute__((ext_vector_type(4)));

#define BARRIER_LGKM() asm volatile("s_waitcnt lgkmcnt(0)\n\ts_barrier" ::: "memory")

__device__ __forceinline__ u32 pk2bf(float a, float b) {
    __hip_bfloat162 h2 = __float22bfloat162_rn(make_float2(a, b));
    u32 r;
    __builtin_memcpy(&r, &h2, 4);
    return r;
}

// Pack weights into per-lane MFMA A-fragment order; parent folded into W1.
// halfword[((kt*16 + nt)*64 + lane)*8 + i] = bf16(W'[nt*16 + (lane&15)][kt*32 + 8*(lane>>4) + i])
__global__ __launch_bounds__(256) void pack_w_kernel(
    const float* __restrict__ W1, const float* __restrict__ W2,
    const float* __restrict__ parent, unsigned short* __restrict__ wp)
{
    int t = blockIdx.x * 256 + threadIdx.x;   // 0..16383
    int sel = t >> 13;
    int tt = t & 8191;
    int lane = tt & 63;
    int nt = (tt >> 6) & 15;
    int kt = tt >> 10;
    int n = nt * 16 + (lane & 15);
    int k0 = kt * 32 + 8 * (lane >> 4);
    const float* W = sel ? W2 : W1;
    const float* src = W + n * 256 + k0;
    f32x4 a = *(const f32x4*)src;
    f32x4 b = *(const f32x4*)(src + 4);
    if (sel == 0) {                            // fold parent into W1
        a *= *(const f32x4*)(parent + k0);
        b *= *(const f32x4*)(parent + k0 + 4);
    }
    u32x4 d;
    d.x = pk2bf(a.x, a.y);
    d.y = pk2bf(a.z, a.w);
    d.z = pk2bf(b.x, b.y);
    d.w = pk2bf(b.z, b.w);
    *(u32x4*)(wp + (size_t)t * 8) = d;
}

__global__ __launch_bounds__(512, 2) void fused_mlp(
    const float* __restrict__ child,
    const float* __restrict__ b1, const float* __restrict__ b2,
    const unsigned short* __restrict__ w1p, const unsigned short* __restrict__ w2p,
    float* __restrict__ out, int n_rows)
{
    // frags: frag (mf, kt) at halfword (mf*8+kt)*512 + lane*8   (mf<4, kt<8)
    __shared__ __align__(16) unsigned short xf[2][16384];  // 2 x 32 KiB x-frags
    __shared__ __align__(16) unsigned short hf[2][16384];  // 2 x 32 KiB h-frags
    __shared__ __align__(16) float bias[512];              // [0..255]=b1, [256..511]=b2

    const int tid = threadIdx.x;
    const int lane = tid & 63;
    const int w = tid >> 6;        // wave 0..7; owns cols [32w, 32w+32) both layers
    const int m16 = lane & 15;
    const int g = lane >> 4;
    const int mfS = w >> 1;        // stage role: rows [16*mfS, +16)
    const int khalf = (w & 1) * 128;

    if (tid < 256) bias[tid] = b1[tid];
    else           bias[tid] = b2[tid - 256];

    // this wave's weight fragments (loaded once; allocator may re-load from
    // L2 per tile — measured equivalent, see R8/R14)
    bf16x8 wA1[2][8], wA2[2][8];
    #pragma unroll
    for (int ntl = 0; ntl < 2; ++ntl) {
        #pragma unroll
        for (int kt = 0; kt < 8; ++kt) {
            wA1[ntl][kt] = *(const bf16x8*)(w1p + (size_t)((kt * 16 + 2 * w + ntl) * 64 + lane) * 8);
            wA2[ntl][kt] = *(const bf16x8*)(w2p + (size_t)((kt * 16 + 2 * w + ntl) * 64 + lane) * 8);
        }
    }
    #pragma unroll
    for (int ntl = 0; ntl < 2; ++ntl) {
        #pragma unroll
        for (int kt = 0; kt < 8; ++kt) {
            asm volatile("" : "+v"(wA1[ntl][kt]));
            asm volatile("" : "+v"(wA2[ntl][kt]));
        }
    }

    const int n_tiles = (n_rows + 63) >> 6;    // 3125 (200000 = 64*3125)

    // transient-held child rows for the NEXT tile (32 VGPRs)
    f32x4 c[8];
    auto load_rows = [&](int tile) {
        long row = (long)tile * 64 + mfS * 16 + m16;
        long lim = (long)n_rows - 1;
        if (row > lim) row = lim;              // clamp: harmless duplicate reads
        const float* cp = child + row * 256 + khalf + 8 * g;
        #pragma unroll
        for (int kt = 0; kt < 4; ++kt) {
            c[2 * kt]     = *(const f32x4*)(cp + kt * 32);
            c[2 * kt + 1] = *(const f32x4*)(cp + kt * 32 + 4);
        }
    };
    auto stage = [&](int buf) {                // cvt held regs -> x-frags
        #pragma unroll
        for (int kt = 0; kt < 4; ++kt) {
            u32x4 u;
            u.x = pk2bf(c[2 * kt].x, c[2 * kt].y);
            u.y = pk2bf(c[2 * kt].z, c[2 * kt].w);
            u.z = pk2bf(c[2 * kt + 1].x, c[2 * kt + 1].y);
            u.w = pk2bf(c[2 * kt + 1].z, c[2 * kt + 1].w);
            *(u32x4*)&xf[buf][((mfS * 8 + (w & 1) * 4 + kt) * 64 + lane) * 8] = u;
        }
    };

    // prologue: stage first tile into xf[0]
    load_rows(blockIdx.x);
    stage(0);
    BARRIER_LGKM();                            // bias + xf[0] ready

    int p = 0;
    for (int tile = blockIdx.x; tile < n_tiles; tile += gridDim.x) {
        const int row0 = tile * 64;
        const int nxt = tile + gridDim.x;
        const bool have_nxt = nxt < n_tiles;   // block-uniform

        // (1) issue next tile's child loads — in flight through layer 1
        if (have_nxt) load_rows(nxt);

        // (2) layer 1: acc1[j][mf] over xf[p]
        f32x4 acc1[2][4];
        #pragma unroll
        for (int j = 0; j < 2; ++j) {
            f32x4 bv = *(const f32x4*)&bias[(2 * w + j) * 16 + 4 * g];
            #pragma unroll
            for (int mf = 0; mf < 4; ++mf) acc1[j][mf] = bv;
        }
        #pragma unroll
        for (int kt = 0; kt < 8; ++kt) {
            #pragma unroll
            for (int mf = 0; mf < 4; ++mf) {
                bf16x8 bfrag = *(const bf16x8*)&xf[p][((mf * 8 + kt) * 64 + lane) * 8];
                acc1[0][mf] = __builtin_amdgcn_mfma_f32_16x16x32_bf16(wA1[0][kt], bfrag, acc1[0][mf], 0, 0, 0);
                acc1[1][mf] = __builtin_amdgcn_mfma_f32_16x16x32_bf16(wA1[1][kt], bfrag, acc1[1][mf], 0, 0, 0);
            }
        }

        // (3) relu + pack h -> hf[p]  (kt2 = w)
        // lane holds h[k2 = 32w + 16j + 4g + r][m = mf*16 + m16]
        //   -> frag (mf, w), lane' = 16*(2j + (g>>1)) + m16, halfword 4*(g&1) + r
        #pragma unroll
        for (int j = 0; j < 2; ++j) {
            #pragma unroll
            for (int mf = 0; mf < 4; ++mf) {
                f32x4 v = acc1[j][mf];
                v.x = fmaxf(v.x, 0.0f); v.y = fmaxf(v.y, 0.0f);
                v.z = fmaxf(v.z, 0.0f); v.w = fmaxf(v.w, 0.0f);
                u32* dst = (u32*)&hf[p][((mf * 8 + w) * 64 + 16 * (2 * j + (g >> 1)) + m16) * 8 + 4 * (g & 1)];
                dst[0] = pk2bf(v.x, v.y);
                dst[1] = pk2bf(v.z, v.w);
            }
        }

        // (4) stage next tile's x-frags into xf[p^1]
        if (have_nxt) stage(p ^ 1);

        // (5) the ONLY barrier: LDS ordering, vmem stays in flight
        BARRIER_LGKM();

        // (6) layer 2 over hf[p] + store out(t)
        f32x4 acc2[2][4];
        #pragma unroll
        for (int j = 0; j < 2; ++j) {
            f32x4 bv = *(const f32x4*)&bias[256 + (2 * w + j) * 16 + 4 * g];
            #pragma unroll
            for (int mf = 0; mf < 4; ++mf) acc2[j][mf] = bv;
        }
        #pragma unroll
        for (int kt = 0; kt < 8; ++kt) {
            #pragma unroll
            for (int mf = 0; mf < 4; ++mf) {
                bf16x8 hfrag = *(const bf16x8*)&hf[p][((mf * 8 + kt) * 64 + lane) * 8];
                acc2[0][mf] = __builtin_amdgcn_mfma_f32_16x16x32_bf16(wA2[0][kt], hfrag, acc2[0][mf], 0, 0, 0);
                acc2[1][mf] = __builtin_amdgcn_mfma_f32_16x16x32_bf16(wA2[1][kt], hfrag, acc2[1][mf], 0, 0, 0);
            }
        }

        // store: lane holds out[m = mf*16+m16][n2 = (2w+j)*16 + 4g + r]
        #pragma unroll
        for (int mf = 0; mf < 4; ++mf) {
            if (row0 + mf * 16 < n_rows) {     // wave-uniform
                float* orow = out + (size_t)(row0 + mf * 16 + m16) * 256 + 4 * g;
                #pragma unroll
                for (int j = 0; j < 2; ++j) {
                    f32x4 v = acc2[j][mf];
                    v.x = fmaxf(v.x, 0.0f); v.y = fmaxf(v.y, 0.0f);
                    v.z = fmaxf(v.z, 0.0f); v.w = fmaxf(v.w, 0.0f);
                    *(f32x4*)(orow + (2 * w + j) * 16) = v;
                }
            }
        }

        p ^= 1;
    }
}

extern "C" void kernel_launch(void* const* d_in, const int* in_sizes, int n_in,
                              void* d_out, int out_size, void* d_ws, size_t ws_size,
                              hipStream_t stream) {
    const float* parent = (const float*)d_in[0];
    const float* child  = (const float*)d_in[1];
    const float* W1     = (const float*)d_in[2];
    const float* b1     = (const float*)d_in[3];
    const float* W2     = (const float*)d_in[4];
    const float* b2     = (const float*)d_in[5];
    float* out = (float*)d_out;

    unsigned short* wp = (unsigned short*)d_ws;   // [0..65535]=W1' frags, [65536..131071]=W2 frags
    const int n_rows = in_sizes[1] / 256;         // 200000

    pack_w_kernel<<<64, 256, 0, stream>>>(W1, W2, parent, wp);
    fused_mlp<<<256, 512, 0, stream>>>(child, b1, b2,
                                       wp, wp + 65536, out, n_rows);
}